// Round 4
// baseline (1376.225 us; speedup 1.0000x reference)
//
#include <hip/hip_runtime.h>

// EdgeClassifierGNN: 3x SAGEConv(mean) + edge MLP on MI355X.
// R2 (second resubmit after broker timeouts): dst-grouped edge MLP (reuse
// B[dst], CSR stores (src,eid) pairs), unroll-4 gathers in sage64, precomp
// fused into SAGE layer 3 epilogue.

__global__ __launch_bounds__(256) void hist_kernel(const int* __restrict__ ei, int E,
                                                   int* __restrict__ cnt) {
    int e = blockIdx.x * blockDim.x + threadIdx.x;
    if (e < E) atomicAdd(&cnt[ei[E + e]], 1);
}

__global__ __launch_bounds__(1024) void scan_kernel(const int* __restrict__ cnt,
                                                    int* __restrict__ rowptr, int N) {
    __shared__ int sums[1024];
    int t = threadIdx.x;
    int chunk = (N + 1023) >> 10;
    int start = t * chunk;
    int end = min(start + chunk, N);
    int s = 0;
    for (int i = start; i < end; ++i) s += cnt[i];
    sums[t] = s;
    __syncthreads();
    for (int off = 1; off < 1024; off <<= 1) {
        int v = (t >= off) ? sums[t - off] : 0;
        __syncthreads();
        sums[t] += v;
        __syncthreads();
    }
    int run = (t == 0) ? 0 : sums[t - 1];
    if (t == 0) rowptr[0] = 0;
    for (int i = start; i < end; ++i) { run += cnt[i]; rowptr[i + 1] = run; }
}

// CSR fill: store (src, edge_id) per slot so downstream kernels get both.
__global__ __launch_bounds__(256) void fill_kernel(const int* __restrict__ ei, int E,
                                                   const int* __restrict__ rowptr,
                                                   int* __restrict__ cursor,
                                                   int2* __restrict__ ce) {
    int e = blockIdx.x * blockDim.x + threadIdx.x;
    if (e >= E) return;
    int s = ei[e], d = ei[E + e];
    int p = rowptr[d] + atomicAdd(&cursor[d], 1);
    ce[p] = make_int2(s, e);
}

// SAGE layer 1: 16 -> 64. One wave per node; 4 sub-groups of 16 lanes each
// gather one neighbor row (64B) per iteration -> rows in flight x2.
__global__ __launch_bounds__(256) void sage16_kernel(
        const float* __restrict__ x, const int* __restrict__ rowptr,
        const int2* __restrict__ ce, const float* __restrict__ Wl,
        const float* __restrict__ Wr, const float* __restrict__ b,
        float* __restrict__ out, int N) {
    int lane = threadIdx.x & 63;
    int wid  = (blockIdx.x * blockDim.x + threadIdx.x) >> 6;
    int nwv  = (gridDim.x * blockDim.x) >> 6;
    int f = lane & 15, g = lane >> 4;
    for (int i = wid; i < N; i += nwv) {
        int s0 = rowptr[i], s1 = rowptr[i + 1];
        float acc0 = 0.f, acc1 = 0.f;
        int j = s0 + g;
        for (; j + 4 < s1; j += 8) {
            int c0 = ce[j].x, c1 = ce[j + 4].x;
            acc0 += x[(size_t)c0 * 16 + f];
            acc1 += x[(size_t)c1 * 16 + f];
        }
        if (j < s1) acc0 += x[(size_t)ce[j].x * 16 + f];
        float acc = acc0 + acc1;
        acc += __shfl_xor(acc, 16);
        acc += __shfl_xor(acc, 32);
        float inv  = 1.0f / fmaxf((float)(s1 - s0), 1.0f);
        float mean = acc * inv;              // lane l holds mean[l&15]
        float xi   = x[(size_t)i * 16 + f];  // lane l holds x[i][l&15]
        float o = b[lane];
        #pragma unroll
        for (int ff = 0; ff < 16; ++ff) {
            float m  = __shfl(mean, ff);
            float xv = __shfl(xi, ff);
            o += m * Wl[ff * 64 + lane];
            o += xv * Wr[ff * 64 + lane];
        }
        out[(size_t)i * 64 + lane] = fmaxf(o, 0.f);
    }
}

// SAGE layer 64 -> 64. One wave per node, lane = channel. Unroll-4 gather.
__global__ __launch_bounds__(256) void sage64_kernel(
        const float* __restrict__ hin, const int* __restrict__ rowptr,
        const int2* __restrict__ ce, const float* __restrict__ Wl,
        const float* __restrict__ Wr, const float* __restrict__ b,
        float* __restrict__ out, int N) {
    int lane = threadIdx.x & 63;
    int wid  = (blockIdx.x * blockDim.x + threadIdx.x) >> 6;
    int nwv  = (gridDim.x * blockDim.x) >> 6;
    for (int i = wid; i < N; i += nwv) {
        int s0 = rowptr[i], s1 = rowptr[i + 1];
        float acc0 = 0.f, acc1 = 0.f, acc2 = 0.f, acc3 = 0.f;
        int j = s0;
        for (; j + 4 <= s1; j += 4) {
            int c0 = ce[j].x, c1 = ce[j + 1].x, c2 = ce[j + 2].x, c3 = ce[j + 3].x;
            acc0 += hin[(size_t)c0 * 64 + lane];
            acc1 += hin[(size_t)c1 * 64 + lane];
            acc2 += hin[(size_t)c2 * 64 + lane];
            acc3 += hin[(size_t)c3 * 64 + lane];
        }
        for (; j < s1; ++j) acc0 += hin[(size_t)ce[j].x * 64 + lane];
        float inv  = 1.0f / fmaxf((float)(s1 - s0), 1.0f);
        float mean = ((acc0 + acc1) + (acc2 + acc3)) * inv;
        float hi   = hin[(size_t)i * 64 + lane];
        float o = b[lane];
        #pragma unroll
        for (int ff = 0; ff < 64; ++ff) {
            float m  = __shfl(mean, ff);
            float hv = __shfl(hi, ff);
            o += m * Wl[ff * 64 + lane];
            o += hv * Wr[ff * 64 + lane];
        }
        out[(size_t)i * 64 + lane] = fmaxf(o, 0.f);
    }
}

// SAGE layer 3 fused with edge-MLP precompute:
// h3 = relu(mean@W3l + h2@W3r + b3) (kept in registers), then
// A[i] = h3 @ Wm1[0:64] + bm1 ; B[i] = h3 @ Wm1[64:128].
__global__ __launch_bounds__(256) void sage64_ab_kernel(
        const float* __restrict__ hin, const int* __restrict__ rowptr,
        const int2* __restrict__ ce, const float* __restrict__ Wl,
        const float* __restrict__ Wr, const float* __restrict__ b,
        const float* __restrict__ Wm1, const float* __restrict__ bm1,
        float* __restrict__ A, float* __restrict__ Bf, int N) {
    int lane = threadIdx.x & 63;
    int wid  = (blockIdx.x * blockDim.x + threadIdx.x) >> 6;
    int nwv  = (gridDim.x * blockDim.x) >> 6;
    for (int i = wid; i < N; i += nwv) {
        int s0 = rowptr[i], s1 = rowptr[i + 1];
        float acc0 = 0.f, acc1 = 0.f, acc2 = 0.f, acc3 = 0.f;
        int j = s0;
        for (; j + 4 <= s1; j += 4) {
            int c0 = ce[j].x, c1 = ce[j + 1].x, c2 = ce[j + 2].x, c3 = ce[j + 3].x;
            acc0 += hin[(size_t)c0 * 64 + lane];
            acc1 += hin[(size_t)c1 * 64 + lane];
            acc2 += hin[(size_t)c2 * 64 + lane];
            acc3 += hin[(size_t)c3 * 64 + lane];
        }
        for (; j < s1; ++j) acc0 += hin[(size_t)ce[j].x * 64 + lane];
        float inv  = 1.0f / fmaxf((float)(s1 - s0), 1.0f);
        float mean = ((acc0 + acc1) + (acc2 + acc3)) * inv;
        float hi   = hin[(size_t)i * 64 + lane];
        float o = b[lane];
        #pragma unroll
        for (int ff = 0; ff < 64; ++ff) {
            float m  = __shfl(mean, ff);
            float hv = __shfl(hi, ff);
            o += m * Wl[ff * 64 + lane];
            o += hv * Wr[ff * 64 + lane];
        }
        float h = fmaxf(o, 0.f);
        float a  = bm1[lane];
        float bb = 0.f;
        #pragma unroll
        for (int ff = 0; ff < 64; ++ff) {
            float hv = __shfl(h, ff);
            a  += hv * Wm1[ff * 64 + lane];
            bb += hv * Wm1[(64 + ff) * 64 + lane];
        }
        A[(size_t)i * 64 + lane]  = a;
        Bf[(size_t)i * 64 + lane] = bb;
    }
}

// Edge MLP, dst-grouped: one wave per dst node, B[d] read once (sequential),
// only A[src] + attr gathered. Two edges per iteration for ILP.
__global__ __launch_bounds__(256) void edge_kernel(
        const float* __restrict__ A, const float* __restrict__ Bf,
        const int* __restrict__ rowptr, const int2* __restrict__ ce,
        const float* __restrict__ attr,
        const float* __restrict__ Wm1, const float* __restrict__ Wm2,
        const float* __restrict__ Wm3, const float* __restrict__ bm2,
        const float* __restrict__ bm3, float* __restrict__ out, int N) {
    int lane = threadIdx.x & 63;
    int wid  = (blockIdx.x * blockDim.x + threadIdx.x) >> 6;
    int nwv  = (gridDim.x * blockDim.x) >> 6;
    int p = lane & 31;
    int obase = lane & 32;          // this half reduces z1[obase..obase+31]
    // Preload weight columns into registers (loop-invariant).
    float wmE[8];
    #pragma unroll
    for (int k = 0; k < 8; ++k) wmE[k] = Wm1[(128 + k) * 64 + lane];
    float wm2[32];
    #pragma unroll
    for (int k = 0; k < 32; ++k) wm2[k] = Wm2[(obase + k) * 32 + p];
    float w3    = Wm3[p];
    float bias2 = bm2[p];
    float bias3 = bm3[0];

    for (int d = wid; d < N; d += nwv) {
        int s0 = rowptr[d], s1 = rowptr[d + 1];
        if (s0 == s1) continue;
        float Bd = Bf[(size_t)d * 64 + lane];
        int j = s0;
        for (; j + 2 <= s1; j += 2) {
            int2 ce0 = ce[j], ce1 = ce[j + 1];
            float a0 = A[(size_t)ce0.x * 64 + lane];
            float a1 = A[(size_t)ce1.x * 64 + lane];
            // lanes 0-7 load edge0 attr, lanes 8-15 edge1 attr
            int eid  = (lane & 8) ? ce1.y : ce0.y;
            float av = (lane < 16) ? attr[(size_t)eid * 8 + (lane & 7)] : 0.f;
            float z0 = Bd + a0, z1 = Bd + a1;
            #pragma unroll
            for (int k = 0; k < 8; ++k) {
                z0 += __shfl(av, k)     * wmE[k];
                z1 += __shfl(av, 8 + k) * wmE[k];
            }
            z0 = fmaxf(z0, 0.f); z1 = fmaxf(z1, 0.f);
            float y0 = 0.f, y1 = 0.f;
            #pragma unroll
            for (int k = 0; k < 32; ++k) {
                y0 += __shfl(z0, obase + k) * wm2[k];
                y1 += __shfl(z1, obase + k) * wm2[k];
            }
            y0 += __shfl_xor(y0, 32);
            y1 += __shfl_xor(y1, 32);
            y0 = fmaxf(y0 + bias2, 0.f) * w3;
            y1 = fmaxf(y1 + bias2, 0.f) * w3;
            float t = (lane < 32) ? y0 : y1;   // half0 -> edge0, half1 -> edge1
            t += __shfl_xor(t, 16);
            t += __shfl_xor(t, 8);
            t += __shfl_xor(t, 4);
            t += __shfl_xor(t, 2);
            t += __shfl_xor(t, 1);
            if (lane == 0)       out[ce0.y] = t + bias3;
            else if (lane == 32) out[ce1.y] = t + bias3;
        }
        if (j < s1) {  // tail edge
            int2 ce0 = ce[j];
            float a0 = A[(size_t)ce0.x * 64 + lane];
            float av = (lane < 8) ? attr[(size_t)ce0.y * 8 + lane] : 0.f;
            float z0 = Bd + a0;
            #pragma unroll
            for (int k = 0; k < 8; ++k) z0 += __shfl(av, k) * wmE[k];
            z0 = fmaxf(z0, 0.f);
            float y0 = 0.f;
            #pragma unroll
            for (int k = 0; k < 32; ++k) y0 += __shfl(z0, obase + k) * wm2[k];
            y0 += __shfl_xor(y0, 32);
            y0 = fmaxf(y0 + bias2, 0.f) * w3;
            float t = (lane < 32) ? y0 : 0.f;
            t += __shfl_xor(t, 16);
            t += __shfl_xor(t, 8);
            t += __shfl_xor(t, 4);
            t += __shfl_xor(t, 2);
            t += __shfl_xor(t, 1);
            if (lane == 0) out[ce0.y] = t + bias3;
        }
    }
}

extern "C" void kernel_launch(void* const* d_in, const int* in_sizes, int n_in,
                              void* d_out, int out_size, void* d_ws, size_t ws_size,
                              hipStream_t stream) {
    const float* x    = (const float*)d_in[0];
    const int*   ei   = (const int*)d_in[1];
    const float* attr = (const float*)d_in[2];
    const float* W1l  = (const float*)d_in[3];
    const float* W1r  = (const float*)d_in[4];
    const float* b1   = (const float*)d_in[5];
    const float* W2l  = (const float*)d_in[6];
    const float* W2r  = (const float*)d_in[7];
    const float* b2   = (const float*)d_in[8];
    const float* W3l  = (const float*)d_in[9];
    const float* W3r  = (const float*)d_in[10];
    const float* b3   = (const float*)d_in[11];
    const float* Wm1  = (const float*)d_in[12];
    const float* bm1  = (const float*)d_in[13];
    const float* Wm2  = (const float*)d_in[14];
    const float* bm2  = (const float*)d_in[15];
    const float* Wm3  = (const float*)d_in[16];
    const float* bm3  = (const float*)d_in[17];
    float* out = (float*)d_out;

    const int N = in_sizes[0] / 16;
    const int E = in_sizes[1] / 2;

    // Workspace layout
    char* ws = (char*)d_ws;
    size_t off = 0;
    int* cnt    = (int*)(ws + off); off += (size_t)N * 4;
    int* cursor = (int*)(ws + off); off += (size_t)N * 4;
    int* rowptr = (int*)(ws + off); off += (size_t)(N + 1) * 4;
    off = (off + 255) & ~(size_t)255;
    int2* ce    = (int2*)(ws + off); off += (size_t)E * 8;
    off = (off + 255) & ~(size_t)255;
    float* buf0 = (float*)(ws + off); off += (size_t)N * 64 * 4;  // h1, later A
    float* buf1 = (float*)(ws + off); off += (size_t)N * 64 * 4;  // h2
    float* buf2 = (float*)(ws + off); off += (size_t)N * 64 * 4;  // B

    hipMemsetAsync(ws, 0, (size_t)N * 8, stream);  // cnt + cursor

    const int TB = 256;
    int ebBlocks = (E + TB - 1) / TB;
    int nwBlocks = (N * 64 + TB - 1) / TB;   // one wave per node

    hist_kernel<<<ebBlocks, TB, 0, stream>>>(ei, E, cnt);
    scan_kernel<<<1, 1024, 0, stream>>>(cnt, rowptr, N);
    fill_kernel<<<ebBlocks, TB, 0, stream>>>(ei, E, rowptr, cursor, ce);

    sage16_kernel<<<nwBlocks, TB, 0, stream>>>(x, rowptr, ce, W1l, W1r, b1, buf0, N);
    sage64_kernel<<<nwBlocks, TB, 0, stream>>>(buf0, rowptr, ce, W2l, W2r, b2, buf1, N);
    sage64_ab_kernel<<<nwBlocks, TB, 0, stream>>>(buf1, rowptr, ce, W3l, W3r, b3,
                                                  Wm1, bm1, buf0, buf2, N);

    edge_kernel<<<nwBlocks, TB, 0, stream>>>(buf0, buf2, rowptr, ce, attr,
                                             Wm1, Wm2, Wm3, bm2, bm3, out, N);
}